// Round 13
// baseline (103.570 us; speedup 1.0000x reference)
//
#include <hip/hip_runtime.h>
#include <math.h>

// B=2, L=1024, D=1024, H=16, HD=64.
// probs_ij = s_ij*nc_j^-0.5 / sum_j(s_ij*nc_j^-0.5)   (N_R^-0.5 cancels)
// s_ij = (1 + dist_ij/64)^(-65.5), dist from bf16-rounded Q,K.
// r13: scores computed ONCE (passA -> P bf16 + colsums, coalesced via LDS
// bounce); vscale folds rnc into V' (+rnc row 64); passB = pure GEMM P@V'.

typedef __attribute__((ext_vector_type(8))) short short8;
typedef __attribute__((ext_vector_type(4))) float f32x4;

__device__ inline unsigned short f2bf(float f) {
  unsigned int u = __float_as_uint(f);
  unsigned int r = (u + 0x7FFFu + ((u >> 16) & 1u)) >> 16;
  return (unsigned short)r;
}
__device__ inline float bf2f(unsigned short s) {
  return __uint_as_float(((unsigned int)s) << 16);
}
__device__ inline float score_fn(float dot, float sq) {
  float d2 = fmaxf(fmaf(-2.f, dot, sq), 1e-12f);
  float sd = __builtin_amdgcn_sqrtf(d2);
  float lg = __builtin_amdgcn_logf(fmaf(sd, 0.015625f, 1.0f));  // log2(1+dist/64)
  return __builtin_amdgcn_exp2f(-65.5f * lg);
}
__device__ inline unsigned int cvtpk(float lo, float hi) {
  unsigned int r;
  asm("v_cvt_pk_bf16_f32 %0, %1, %2" : "=v"(r) : "v"(lo), "v"(hi));
  return r;
}
#define GLD16(lptr, gptr)                                                      \
  __builtin_amdgcn_global_load_lds(                                            \
      (const __attribute__((address_space(1))) void*)(gptr),                   \
      (__attribute__((address_space(3))) void*)(lptr), 16, 0, 0)

// ---------------------------------------------------------------------------
// prep: blocks [0,2048) = x f32->bf16; blocks [2048,6144) = 4 weight transposes
__global__ __launch_bounds__(256) void prep(const float* __restrict__ x,
                                            unsigned short* __restrict__ xb,
                                            const float* __restrict__ W0,
                                            const float* __restrict__ W1,
                                            const float* __restrict__ W2,
                                            const float* __restrict__ W3,
                                            unsigned short* __restrict__ T0,
                                            unsigned short* __restrict__ T1,
                                            unsigned short* __restrict__ T2,
                                            unsigned short* __restrict__ T3) {
  __shared__ float T[32][33];
  int bx = blockIdx.x;
  if (bx < 2048) {
    int i = bx * 256 + threadIdx.x;
    float4 v = ((const float4*)x)[i];
    xb[4 * i + 0] = f2bf(v.x);
    xb[4 * i + 1] = f2bf(v.y);
    xb[4 * i + 2] = f2bf(v.z);
    xb[4 * i + 3] = f2bf(v.w);
    return;
  }
  int idx = bx - 2048;
  int z = idx >> 10, rem = idx & 1023;
  const float* W = z == 0 ? W0 : z == 1 ? W1 : z == 2 ? W2 : W3;
  unsigned short* WT = z == 0 ? T0 : z == 1 ? T1 : z == 2 ? T2 : T3;
  int k0 = (rem >> 5) * 32, n0 = (rem & 31) * 32;
  int c = threadIdx.x & 31, r8 = threadIdx.x >> 5;
#pragma unroll
  for (int it = 0; it < 4; ++it) {
    int rr = r8 + it * 8;
    T[rr][c] = W[(size_t)(k0 + rr) * 1024 + n0 + c];
  }
  __syncthreads();
#pragma unroll
  for (int it = 0; it < 4; ++it) {
    int rr = r8 + it * 8;
    WT[(size_t)(n0 + rr) * 1024 + k0 + c] = f2bf(T[c][rr]);
  }
}

// ---------------------------------------------------------------------------
// QKV GEMM: BM=BN=128, BK=64, 512 thr / 8 waves (2x4), 64x32 per wave.
// mode 0 additionally emits per-row sum-of-squares of the bf16 output (q2/k2).
__global__ __launch_bounds__(512, 2) void gemm128k64(const unsigned short* __restrict__ A,
                                                     const unsigned short* __restrict__ B0,
                                                     const unsigned short* __restrict__ B1,
                                                     const unsigned short* __restrict__ B2,
                                                     const float* __restrict__ c0,
                                                     const float* __restrict__ c1,
                                                     const float* __restrict__ c2,
                                                     void* __restrict__ Y0,
                                                     void* __restrict__ Y1,
                                                     void* __restrict__ Y2,
                                                     float* __restrict__ sq0,
                                                     float* __restrict__ sq1,
                                                     float* __restrict__ sq2,
                                                     int m0, int m1, int m2) {
  int z = blockIdx.z;
  const unsigned short* BT = z == 0 ? B0 : z == 1 ? B1 : B2;
  const float* bias = z == 0 ? c0 : z == 1 ? c1 : c2;
  void* Y = z == 0 ? Y0 : z == 1 ? Y1 : Y2;
  float* sq = z == 0 ? sq0 : z == 1 ? sq1 : sq2;
  int mode = z == 0 ? m0 : z == 1 ? m1 : m2;

  __shared__ __align__(16) unsigned short As[2][128 * 64];
  __shared__ __align__(16) unsigned short Bs[2][128 * 64];
  int tid = threadIdx.x;
  int w = tid >> 6, l = tid & 63, g = l >> 4, l15 = l & 15;
  int wm = w >> 2, wn = w & 3;
  int bm = blockIdx.x * 128, bn = blockIdx.y * 128;
  const int x7 = l15 & 7;

  const int i0 = tid, i1 = tid + 512;
  const int r0 = i0 >> 3, s0 = (i0 & 7) ^ (r0 & 7);
  const int r1 = i1 >> 3, s1 = (i1 & 7) ^ (r1 & 7);

  GLD16(&As[0][i0 * 8], &A[(size_t)(bm + r0) * 1024 + s0 * 8]);
  GLD16(&As[0][i1 * 8], &A[(size_t)(bm + r1) * 1024 + s1 * 8]);
  GLD16(&Bs[0][i0 * 8], &BT[(size_t)(bn + r0) * 1024 + s0 * 8]);
  GLD16(&Bs[0][i1 * 8], &BT[(size_t)(bn + r1) * 1024 + s1 * 8]);

  f32x4 acc[4][2];
#pragma unroll
  for (int mi = 0; mi < 4; ++mi)
#pragma unroll
    for (int ni = 0; ni < 2; ++ni)
#pragma unroll
      for (int r = 0; r < 4; ++r) acc[mi][ni][r] = 0.f;

  __syncthreads();
  for (int t = 0; t < 16; ++t) {
    int cur = t & 1;
    if (t < 15) {
      int kn = (t + 1) * 64;
      GLD16(&As[cur ^ 1][i0 * 8], &A[(size_t)(bm + r0) * 1024 + kn + s0 * 8]);
      GLD16(&As[cur ^ 1][i1 * 8], &A[(size_t)(bm + r1) * 1024 + kn + s1 * 8]);
      GLD16(&Bs[cur ^ 1][i0 * 8], &BT[(size_t)(bn + r0) * 1024 + kn + s0 * 8]);
      GLD16(&Bs[cur ^ 1][i1 * 8], &BT[(size_t)(bn + r1) * 1024 + kn + s1 * 8]);
    }
#pragma unroll
    for (int kc = 0; kc < 2; ++kc) {
      const int cread = (((kc << 2) + g) ^ x7) * 8;
      short8 a[4], b[2];
#pragma unroll
      for (int mi = 0; mi < 4; ++mi)
        a[mi] = *(const short8*)&As[cur][(wm * 64 + mi * 16 + l15) * 64 + cread];
#pragma unroll
      for (int ni = 0; ni < 2; ++ni)
        b[ni] = *(const short8*)&Bs[cur][(wn * 32 + ni * 16 + l15) * 64 + cread];
#pragma unroll
      for (int mi = 0; mi < 4; ++mi)
#pragma unroll
        for (int ni = 0; ni < 2; ++ni)
          acc[mi][ni] = __builtin_amdgcn_mfma_f32_16x16x32_bf16(a[mi], b[ni], acc[mi][ni], 0, 0, 0);
    }
    __syncthreads();
  }

  float rowsq[4][4];
#pragma unroll
  for (int mi = 0; mi < 4; ++mi)
#pragma unroll
    for (int r = 0; r < 4; ++r) rowsq[mi][r] = 0.f;

#pragma unroll
  for (int ni = 0; ni < 2; ++ni) {
    int n = bn + wn * 32 + ni * 16 + l15;
    float bv = bias[n];
#pragma unroll
    for (int mi = 0; mi < 4; ++mi) {
#pragma unroll
      for (int r = 0; r < 4; ++r) {
        int m = bm + wm * 64 + mi * 16 + 4 * g + r;
        float v = acc[mi][ni][r] + bv;
        if (mode == 0) {
          int b = m >> 10, ll = m & 1023, h = n >> 6, hd = n & 63;
          unsigned short ush = f2bf(v);
          ((unsigned short*)Y)[(((size_t)(b * 16 + h) * 1024) + ll) * 64 + hd] = ush;
          float f = bf2f(ush);
          rowsq[mi][r] = fmaf(f, f, rowsq[mi][r]);
        } else if (mode == 1) {
          int b = m >> 10, ll = m & 1023, h = n >> 6, hd = n & 63;
          int jp = (ll & ~31) | (((ll >> 2) & 3) * 8 + ((ll >> 4) & 1) * 4 + (ll & 3));
          ((unsigned short*)Y)[(((size_t)(b * 16 + h) * 64) + hd) * 1024 + jp] = f2bf(v);
        } else {
          ((float*)Y)[(size_t)m * 1024 + n] = v;
        }
      }
    }
  }

  if (sq != nullptr) {
    float* Sq = (float*)&As[0][0];  // reuse (all compute past final barrier)
#pragma unroll
    for (int mi = 0; mi < 4; ++mi)
#pragma unroll
      for (int r = 0; r < 4; ++r) {
        float s = rowsq[mi][r];
        s += __shfl_xor(s, 1);
        s += __shfl_xor(s, 2);
        s += __shfl_xor(s, 4);
        s += __shfl_xor(s, 8);
        rowsq[mi][r] = s;
      }
    if (l15 == 0) {
#pragma unroll
      for (int mi = 0; mi < 4; ++mi)
#pragma unroll
        for (int r = 0; r < 4; ++r)
          Sq[(wm * 4 + wn) * 64 + mi * 16 + 4 * g + r] = rowsq[mi][r];
    }
    __syncthreads();
    if (tid < 256) {
      int rr = tid & 127, hh = tid >> 7;
      float s = Sq[((rr >> 6) * 4 + 2 * hh) * 64 + (rr & 63)] +
                Sq[((rr >> 6) * 4 + 2 * hh + 1) * 64 + (rr & 63)];
      int m = bm + rr, b = m >> 10, ll = m & 1023;
      int h = (bn >> 6) + hh;
      sq[(size_t)(b * 16 + h) * 1024 + ll] = s;
    }
  }
}

// ---------------------------------------------------------------------------
// 64-cube MFMA GEMM — output projection.
__global__ __launch_bounds__(256) void gemm_st(const unsigned short* __restrict__ A,
                                               const unsigned short* __restrict__ BT,
                                               const float* __restrict__ bias,
                                               float* __restrict__ Y) {
  __shared__ __align__(16) unsigned short As[2][64 * 64];
  __shared__ __align__(16) unsigned short Bs[2][64 * 64];
  int tid = threadIdx.x;
  int w = tid >> 6, l = tid & 63, g = l >> 4, l15 = l & 15;
  int bm = blockIdx.x * 64, bn = blockIdx.y * 64;
  const int arow = w * 16 + l15;
  const int x7 = l15 & 7;

  const int i0s = tid, i1s = 256 + tid;
  const int r0 = i0s >> 3, s0 = (i0s & 7) ^ (r0 & 7);
  const int r1 = i1s >> 3, s1 = (i1s & 7) ^ (r1 & 7);

  GLD16(&As[0][i0s * 8], &A[(size_t)(bm + r0) * 1024 + s0 * 8]);
  GLD16(&As[0][i1s * 8], &A[(size_t)(bm + r1) * 1024 + s1 * 8]);
  GLD16(&Bs[0][i0s * 8], &BT[(size_t)(bn + r0) * 1024 + s0 * 8]);
  GLD16(&Bs[0][i1s * 8], &BT[(size_t)(bn + r1) * 1024 + s1 * 8]);

  f32x4 acc[4];
#pragma unroll
  for (int t = 0; t < 4; ++t)
#pragma unroll
    for (int r = 0; r < 4; ++r) acc[t][r] = 0.f;

  __syncthreads();
  for (int t = 0; t < 16; ++t) {
    int cur = t & 1;
    if (t < 15) {
      int kn = (t + 1) * 64;
      GLD16(&As[cur ^ 1][i0s * 8], &A[(size_t)(bm + r0) * 1024 + kn + s0 * 8]);
      GLD16(&As[cur ^ 1][i1s * 8], &A[(size_t)(bm + r1) * 1024 + kn + s1 * 8]);
      GLD16(&Bs[cur ^ 1][i0s * 8], &BT[(size_t)(bn + r0) * 1024 + kn + s0 * 8]);
      GLD16(&Bs[cur ^ 1][i1s * 8], &BT[(size_t)(bn + r1) * 1024 + kn + s1 * 8]);
    }
#pragma unroll
    for (int kc = 0; kc < 2; ++kc) {
      short8 a = *(const short8*)&As[cur][arow * 64 + ((kc * 4 + g) ^ x7) * 8];
#pragma unroll
      for (int tt = 0; tt < 4; ++tt) {
        short8 b = *(const short8*)&Bs[cur][(tt * 16 + l15) * 64 + ((kc * 4 + g) ^ x7) * 8];
        acc[tt] = __builtin_amdgcn_mfma_f32_16x16x32_bf16(a, b, acc[tt], 0, 0, 0);
      }
    }
    __syncthreads();
  }

#pragma unroll
  for (int t = 0; t < 4; ++t) {
    int n = bn + 16 * t + l15;
    float bv = bias[n];
#pragma unroll
    for (int r = 0; r < 4; ++r) {
      int m = bm + w * 16 + 4 * g + r;
      Y[(size_t)m * 1024 + n] = acc[t][r] + bv;
    }
  }
}

// ---------------------------------------------------------------------------
// passA: scores once. Block (bh, jt64): K frags pinned, Q streamed via GLD16.
// Emits P[bh][i][jp] (bf16, permuted layout, COALESCED via LDS bounce) and
// rnc = colsum^-0.5.
__global__ __launch_bounds__(256, 4) void passA(const unsigned short* __restrict__ Qb,
                                                const unsigned short* __restrict__ Kb,
                                                const float* __restrict__ q2,
                                                const float* __restrict__ k2,
                                                unsigned short* __restrict__ P,
                                                float* __restrict__ rnc) {
  __shared__ __align__(16) unsigned short Qd[2][64 * 64];
  __shared__ __align__(16) float q2s[1024];
  __shared__ __align__(16) unsigned int Pb[2][64][36];  // rows padded to 144B
  __shared__ float colred[4][64];
  int bh = blockIdx.x, jt = blockIdx.y;
  int tid = threadIdx.x, w = tid >> 6, l = tid & 63;
  int g = l >> 4, l15 = l & 15;
  const int x7 = l15 & 7;
  const unsigned short* Qp = Qb + (size_t)bh * 65536;
  const unsigned short* Kp = Kb + (size_t)bh * 65536;

  const int i0s = tid, i1s = 256 + tid;
  const int r0 = i0s >> 3, s0 = (i0s & 7) ^ (r0 & 7);
  const int r1 = i1s >> 3, s1 = (i1s & 7) ^ (r1 & 7);

  GLD16(&q2s[tid * 4], q2 + (size_t)bh * 1024 + tid * 4);
  GLD16(&Qd[0][i0s * 8], Qp + (size_t)r0 * 64 + s0 * 8);
  GLD16(&Qd[0][i1s * 8], Qp + (size_t)r1 * 64 + s1 * 8);

  // K fragments (A-operand, m = j) pinned: 4 j-subtiles x 2 k-halves
  short8 ak[4][2];
#pragma unroll
  for (int tp = 0; tp < 4; ++tp) {
#pragma unroll
    for (int hf = 0; hf < 2; ++hf)
      ak[tp][hf] = *(const short8*)&Kp[(size_t)(jt * 64 + 16 * tp + l15) * 64 + hf * 32 + 8 * g];
  }
  float k2v[16];
#pragma unroll
  for (int tp = 0; tp < 4; ++tp) {
    float4 kk = *(const float4*)&k2[(size_t)bh * 1024 + jt * 64 + 16 * tp + 4 * g];
    k2v[tp * 4 + 0] = kk.x; k2v[tp * 4 + 1] = kk.y;
    k2v[tp * 4 + 2] = kk.z; k2v[tp * 4 + 3] = kk.w;
  }
  float colpart[16];
#pragma unroll
  for (int q = 0; q < 16; ++q) colpart[q] = 0.f;

  const int iloc = w * 16 + l15;
  const int pr0 = tid >> 3, pc0 = tid & 7;           // P-store chunk 0
  const int pr1 = (tid + 256) >> 3, pc1 = tid & 7;   // P-store chunk 1

  __syncthreads();
  for (int t = 0; t < 16; ++t) {
    int cur = t & 1;
    if (t < 15) {
      int inx = (t + 1) * 64;
      GLD16(&Qd[cur ^ 1][i0s * 8], Qp + (size_t)(inx + r0) * 64 + s0 * 8);
      GLD16(&Qd[cur ^ 1][i1s * 8], Qp + (size_t)(inx + r1) * 64 + s1 * 8);
    }
    int rowb = iloc * 64;
    short8 bq0 = *(const short8*)&Qd[cur][rowb + ((g) ^ x7) * 8];
    short8 bq1 = *(const short8*)&Qd[cur][rowb + ((4 + g) ^ x7) * 8];
    float q2l = q2s[t * 64 + iloc];

    float sc[16];
#pragma unroll
    for (int tp = 0; tp < 4; ++tp) {
      f32x4 cf;
#pragma unroll
      for (int r = 0; r < 4; ++r) cf[r] = 0.f;
      cf = __builtin_amdgcn_mfma_f32_16x16x32_bf16(ak[tp][0], bq0, cf, 0, 0, 0);
      cf = __builtin_amdgcn_mfma_f32_16x16x32_bf16(ak[tp][1], bq1, cf, 0, 0, 0);
#pragma unroll
      for (int r = 0; r < 4; ++r)
        sc[tp * 4 + r] = score_fn(cf[r], q2l + k2v[tp * 4 + r]);
    }
#pragma unroll
    for (int q = 0; q < 16; ++q) colpart[q] += sc[q];

    // write to bounce buffer in jp-permuted bf16 layout
#pragma unroll
    for (int tp = 0; tp < 4; ++tp) {
#pragma unroll
      for (int rp = 0; rp < 2; ++rp) {
        int dwidx = 16 * (tp >> 1) + 4 * g + 2 * (tp & 1) + rp;
        Pb[cur][iloc][dwidx] = cvtpk(sc[tp * 4 + 2 * rp], sc[tp * 4 + 2 * rp + 1]);
      }
    }
    __syncthreads();
    // coalesced P store: 512 chunks of 16B (this tile's 64 rows x 128B)
    {
      short8 v0 = *(const short8*)((const char*)&Pb[cur][0][0] + 144 * pr0 + 16 * pc0);
      short8 v1 = *(const short8*)((const char*)&Pb[cur][0][0] + 144 * pr1 + 16 * pc1);
      *(short8*)&P[((size_t)bh * 1024 + t * 64 + pr0) * 1024 + jt * 64 + 8 * pc0] = v0;
      *(short8*)&P[((size_t)bh * 1024 + t * 64 + pr1) * 1024 + jt * 64 + 8 * pc1] = v1;
    }
  }

  // reduce colpart over the 16 i-lanes (l15), then across waves
#pragma unroll
  for (int q = 0; q < 16; ++q) {
    float v = colpart[q];
    v += __shfl_xor(v, 1);
    v += __shfl_xor(v, 2);
    v += __shfl_xor(v, 4);
    v += __shfl_xor(v, 8);
    colpart[q] = v;
  }
  if (l15 == 0) {
#pragma unroll
    for (int q = 0; q < 16; ++q)
      colred[w][16 * (q >> 2) + 4 * g + (q & 3)] = colpart[q];
  }
  __syncthreads();
  if (tid < 64) {
    float s = colred[0][tid] + colred[1][tid] + colred[2][tid] + colred[3][tid];
    rnc[(size_t)bh * 1024 + jt * 64 + tid] = __builtin_amdgcn_rsqf(s);
  }
}

// ---------------------------------------------------------------------------
// Build V'[bh][80][1024] (permuted cols): rows 0-63 = VTp*rnc, row 64 = rnc,
// rows 65-79 = 0. grid (32 bh, 80 rows), 256 thr x 4 elems.
__global__ __launch_bounds__(256) void vscale(const unsigned short* __restrict__ VTp,
                                              const float* __restrict__ rnc,
                                              unsigned short* __restrict__ Vs) {
  int bh = blockIdx.x, row = blockIdx.y;
  int j4 = threadIdx.x * 4;
  unsigned short out[4];
#pragma unroll
  for (int e = 0; e < 4; ++e) {
    int jp = j4 + e;
    int p = jp & 31;
    int gg = (p >> 3) & 3, jj = (p >> 2) & 1, rr = p & 3;
    int jtrue = (jp & ~31) | (16 * jj + 4 * gg + rr);
    float rv = rnc[(size_t)bh * 1024 + jtrue];
    if (row < 64) {
      float v = bf2f(VTp[((size_t)bh * 64 + row) * 1024 + jp]);
      out[e] = f2bf(v * rv);
    } else if (row == 64) {
      out[e] = f2bf(rv);
    } else {
      out[e] = 0;
    }
  }
  *(unsigned long long*)&Vs[((size_t)bh * 80 + row) * 1024 + j4] = *(unsigned long long*)out;
}

// ---------------------------------------------------------------------------
// passB: pure GEMM O = P @ V' (+denominator from n-tile 4 = rnc row).
// grid (32 bh, 16 it64), 256 thr; streams 16 j-tiles of 64 via GLD16 dbuf.
__global__ __launch_bounds__(256, 4) void passB(const unsigned short* __restrict__ P,
                                                const unsigned short* __restrict__ Vs,
                                                unsigned short* __restrict__ AO) {
  __shared__ __align__(16) unsigned short Pd[2][64 * 64];
  __shared__ __align__(16) unsigned short Vd[2][80 * 64];
  int bh = blockIdx.x, it = blockIdx.y;
  int tid = threadIdx.x, w = tid >> 6, l = tid & 63;
  int g = l >> 4, l15 = l & 15;
  const int x7 = l15 & 7;
  const unsigned short* Pp = P + (size_t)bh * 1048576;
  const unsigned short* Vp = Vs + (size_t)bh * 81920;
  int b = bh >> 4, h = bh & 15;

  const int cP0 = tid, cP1 = tid + 256;
  const int rP0 = cP0 >> 3, sP0 = (cP0 & 7) ^ (rP0 & 7);
  const int rP1 = cP1 >> 3, sP1 = (cP1 & 7) ^ (rP1 & 7);
  const int cV0 = tid, cV1 = tid + 256, cV2 = tid + 512;
  const int rV0 = cV0 >> 3, sV0 = (cV0 & 7) ^ (rV0 & 7);
  const int rV1 = cV1 >> 3, sV1 = (cV1 & 7) ^ (rV1 & 7);
  const int rV2 = cV2 >> 3, sV2 = (cV2 & 7) ^ (rV2 & 7);

  GLD16(&Pd[0][cP0 * 8], Pp + (size_t)(it * 64 + rP0) * 1024 + sP0 * 8);
  GLD16(&Pd[0][cP1 * 8], Pp + (size_t)(it * 64 + rP1) * 1024 + sP1 * 8);
  GLD16(&Vd[0][cV0 * 8], Vp + (size_t)rV0 * 1024 + sV0 * 8);
  GLD16(&Vd[0][cV1 * 8], Vp + (size_t)rV1 * 1024 + sV1 * 8);
  if (tid < 128) GLD16(&Vd[0][cV2 * 8], Vp + (size_t)rV2 * 1024 + sV2 * 8);

  f32x4 o[5];
#pragma unroll
  for (int t5 = 0; t5 < 5; ++t5)
#pragma unroll
    for (int r = 0; r < 4; ++r) o[t5][r] = 0.f;

  __syncthreads();
  for (int t = 0; t < 16; ++t) {
    int cur = t & 1;
    if (t < 15) {
      int jn = (t + 1) * 64;
      GLD16(&Pd[cur ^ 1][cP0 * 8], Pp + (size_t)(it * 64 + rP0) * 1024 + jn + sP0 * 8);
      GLD16(&Pd[cur ^ 1][cP1 * 8], Pp + (size_t)(it * 64 + rP1) * 1024 + jn + sP1 * 8);
      GLD16(&Vd[cur ^ 1][cV0 * 8], Vp + (size_t)rV0 * 1024 + jn + sV0 * 8);
      GLD16(&Vd[cur ^ 1][cV1 * 8], Vp + (size_t)rV1 * 1024 + jn + sV1 * 8);
      if (tid < 128) GLD16(&Vd[cur ^ 1][cV2 * 8], Vp + (size_t)rV2 * 1024 + jn + sV2 * 8);
    }
    int rowb = (w * 16 + l15) * 64;
    short8 pa0 = *(const short8*)&Pd[cur][rowb + ((g) ^ x7) * 8];
    short8 pa1 = *(const short8*)&Pd[cur][rowb + ((4 + g) ^ x7) * 8];
#pragma unroll
    for (int t5 = 0; t5 < 5; ++t5) {
      int vrow = (16 * t5 + l15) * 64;
      short8 bv0 = *(const short8*)&Vd[cur][vrow + ((g) ^ x7) * 8];
      short8 bv1 = *(const short8*)&Vd[cur][vrow + ((4 + g) ^ x7) * 8];
      __builtin_amdgcn_s_setprio(1);
      o[t5] = __builtin_amdgcn_mfma_f32_16x16x32_bf16(pa0, bv0, o[t5], 0, 0, 0);
      o[t5] = __builtin_amdgcn_mfma_f32_16x16x32_bf16(pa1, bv1, o[t5], 0, 0, 0);
      __builtin_amdgcn_s_setprio(0);
    }
    __syncthreads();
  }

  float dv[4];
#pragma unroll
  for (int r = 0; r < 4; ++r) dv[r] = __shfl(o[4][r], 16 * g);

#pragma unroll
  for (int t5 = 0; t5 < 4; ++t5) {
#pragma unroll
    for (int r = 0; r < 4; ++r) {
      int m = b * 1024 + it * 64 + w * 16 + 4 * g + r;
      int n = h * 64 + 16 * t5 + l15;
      AO[(size_t)m * 1024 + n] = f2bf(o[t5][r] / dv[r]);
    }
  }
}

// ---------------------------------------------------------------------------
extern "C" void kernel_launch(void* const* d_in, const int* in_sizes, int n_in,
                              void* d_out, int out_size, void* d_ws, size_t ws_size,
                              hipStream_t stream) {
  const float* x  = (const float*)d_in[0];
  const float* WQ = (const float*)d_in[1];
  const float* bQ = (const float*)d_in[2];
  const float* WK = (const float*)d_in[3];
  const float* bK = (const float*)d_in[4];
  const float* WV = (const float*)d_in[5];
  const float* bV = (const float*)d_in[6];
  const float* WO = (const float*)d_in[7];
  const float* bO = (const float*)d_in[8];

  char* base = (char*)d_ws;
  unsigned short* xb  = (unsigned short*)(base);
  unsigned short* WQT = (unsigned short*)(base + (4u  << 20));
  unsigned short* WKT = (unsigned short*)(base + (6u  << 20));
  unsigned short* WVT = (unsigned short*)(base + (8u  << 20));
  unsigned short* WOT = (unsigned short*)(base + (10u << 20));
  unsigned short* Qb  = (unsigned short*)(base + (12u << 20));
  unsigned short* Kb  = (unsigned short*)(base + (16u << 20));
  unsigned short* VTp = (unsigned short*)(base + (20u << 20));
  unsigned short* AOb = (unsigned short*)(base + (24u << 20));
  float* q2  = (float*)(base + (28u << 20));
  float* k2  = (float*)(base + (28u << 20) + (128u << 10));
  float* rnc = (float*)(base + (28u << 20) + (256u << 10));
  unsigned short* Vs = (unsigned short*)(base + (30u << 20));  // 5.25 MB
  unsigned short* P  = (unsigned short*)(base + (36u << 20));  // 64 MB

  prep<<<6144, 256, 0, stream>>>(x, xb, WQ, WK, WV, WO, WQT, WKT, WVT, WOT);

  gemm128k64<<<dim3(16, 8, 3), 512, 0, stream>>>(xb, WQT, WKT, WVT, bQ, bK, bV,
                                                 Qb, Kb, VTp, q2, k2, nullptr,
                                                 0, 0, 1);

  passA<<<dim3(32, 16), 256, 0, stream>>>(Qb, Kb, q2, k2, P, rnc);
  vscale<<<dim3(32, 80), 256, 0, stream>>>(VTp, rnc, Vs);
  passB<<<dim3(32, 16), 256, 0, stream>>>(P, Vs, AOb);

  gemm_st<<<dim3(32, 16), 256, 0, stream>>>(AOb, WOT, bO, (float*)d_out);
}

// Round 14
// 98.284 us; speedup vs baseline: 1.0538x; 1.0538x over previous
//
#include <hip/hip_runtime.h>
#include <math.h>

// B=2, L=1024, D=1024, H=16, HD=64.
// probs_ij = s_ij*nc_j^-0.5 / sum_j(s_ij*nc_j^-0.5)   (N_R^-0.5 cancels)
// s_ij = (1 + dist_ij/64)^(-65.5), dist from bf16-rounded Q,K.
// r14 = r11 base + counted-vmcnt 3-buffer pipelines in colsum/attn (T3/T4).

typedef __attribute__((ext_vector_type(8))) short short8;
typedef __attribute__((ext_vector_type(4))) float f32x4;

__device__ inline unsigned short f2bf(float f) {
  unsigned int u = __float_as_uint(f);
  unsigned int r = (u + 0x7FFFu + ((u >> 16) & 1u)) >> 16;
  return (unsigned short)r;
}
__device__ inline float bf2f(unsigned short s) {
  return __uint_as_float(((unsigned int)s) << 16);
}
__device__ inline float score_fn(float dot, float sq) {
  float d2 = fmaxf(fmaf(-2.f, dot, sq), 1e-12f);
  float sd = __builtin_amdgcn_sqrtf(d2);
  float lg = __builtin_amdgcn_logf(fmaf(sd, 0.015625f, 1.0f));  // log2(1+dist/64)
  return __builtin_amdgcn_exp2f(-65.5f * lg);
}
__device__ inline unsigned int cvtpk(float lo, float hi) {
  unsigned int r;
  asm("v_cvt_pk_bf16_f32 %0, %1, %2" : "=v"(r) : "v"(lo), "v"(hi));
  return r;
}
#define GLD16(lptr, gptr)                                                      \
  __builtin_amdgcn_global_load_lds(                                            \
      (const __attribute__((address_space(1))) void*)(gptr),                   \
      (__attribute__((address_space(3))) void*)(lptr), 16, 0, 0)
#define MEMFENCE() asm volatile("" ::: "memory")
#define HARD_BARRIER()                 \
  do {                                 \
    __builtin_amdgcn_s_barrier();      \
    MEMFENCE();                        \
  } while (0)

// ---------------------------------------------------------------------------
// prep: blocks [0,2048) = x f32->bf16; blocks [2048,6144) = 4 weight transposes
__global__ __launch_bounds__(256) void prep(const float* __restrict__ x,
                                            unsigned short* __restrict__ xb,
                                            const float* __restrict__ W0,
                                            const float* __restrict__ W1,
                                            const float* __restrict__ W2,
                                            const float* __restrict__ W3,
                                            unsigned short* __restrict__ T0,
                                            unsigned short* __restrict__ T1,
                                            unsigned short* __restrict__ T2,
                                            unsigned short* __restrict__ T3) {
  __shared__ float T[32][33];
  int bx = blockIdx.x;
  if (bx < 2048) {
    int i = bx * 256 + threadIdx.x;
    float4 v = ((const float4*)x)[i];
    xb[4 * i + 0] = f2bf(v.x);
    xb[4 * i + 1] = f2bf(v.y);
    xb[4 * i + 2] = f2bf(v.z);
    xb[4 * i + 3] = f2bf(v.w);
    return;
  }
  int idx = bx - 2048;
  int z = idx >> 10, rem = idx & 1023;
  const float* W = z == 0 ? W0 : z == 1 ? W1 : z == 2 ? W2 : W3;
  unsigned short* WT = z == 0 ? T0 : z == 1 ? T1 : z == 2 ? T2 : T3;
  int k0 = (rem >> 5) * 32, n0 = (rem & 31) * 32;
  int c = threadIdx.x & 31, r8 = threadIdx.x >> 5;
#pragma unroll
  for (int it = 0; it < 4; ++it) {
    int rr = r8 + it * 8;
    T[rr][c] = W[(size_t)(k0 + rr) * 1024 + n0 + c];
  }
  __syncthreads();
#pragma unroll
  for (int it = 0; it < 4; ++it) {
    int rr = r8 + it * 8;
    WT[(size_t)(n0 + rr) * 1024 + k0 + c] = f2bf(T[c][rr]);
  }
}

// ---------------------------------------------------------------------------
// QKV GEMM: BM=BN=128, BK=64, 512 thr / 8 waves (2x4), 64x32 per wave.
// mode 0 additionally emits per-row sum-of-squares of the bf16 output (q2/k2).
__global__ __launch_bounds__(512, 2) void gemm128k64(const unsigned short* __restrict__ A,
                                                     const unsigned short* __restrict__ B0,
                                                     const unsigned short* __restrict__ B1,
                                                     const unsigned short* __restrict__ B2,
                                                     const float* __restrict__ c0,
                                                     const float* __restrict__ c1,
                                                     const float* __restrict__ c2,
                                                     void* __restrict__ Y0,
                                                     void* __restrict__ Y1,
                                                     void* __restrict__ Y2,
                                                     float* __restrict__ sq0,
                                                     float* __restrict__ sq1,
                                                     float* __restrict__ sq2,
                                                     int m0, int m1, int m2) {
  int z = blockIdx.z;
  const unsigned short* BT = z == 0 ? B0 : z == 1 ? B1 : B2;
  const float* bias = z == 0 ? c0 : z == 1 ? c1 : c2;
  void* Y = z == 0 ? Y0 : z == 1 ? Y1 : Y2;
  float* sq = z == 0 ? sq0 : z == 1 ? sq1 : sq2;
  int mode = z == 0 ? m0 : z == 1 ? m1 : m2;

  __shared__ __align__(16) unsigned short As[2][128 * 64];
  __shared__ __align__(16) unsigned short Bs[2][128 * 64];
  int tid = threadIdx.x;
  int w = tid >> 6, l = tid & 63, g = l >> 4, l15 = l & 15;
  int wm = w >> 2, wn = w & 3;
  int bm = blockIdx.x * 128, bn = blockIdx.y * 128;
  const int x7 = l15 & 7;

  const int i0 = tid, i1 = tid + 512;
  const int r0 = i0 >> 3, s0 = (i0 & 7) ^ (r0 & 7);
  const int r1 = i1 >> 3, s1 = (i1 & 7) ^ (r1 & 7);

  GLD16(&As[0][i0 * 8], &A[(size_t)(bm + r0) * 1024 + s0 * 8]);
  GLD16(&As[0][i1 * 8], &A[(size_t)(bm + r1) * 1024 + s1 * 8]);
  GLD16(&Bs[0][i0 * 8], &BT[(size_t)(bn + r0) * 1024 + s0 * 8]);
  GLD16(&Bs[0][i1 * 8], &BT[(size_t)(bn + r1) * 1024 + s1 * 8]);

  f32x4 acc[4][2];
#pragma unroll
  for (int mi = 0; mi < 4; ++mi)
#pragma unroll
    for (int ni = 0; ni < 2; ++ni)
#pragma unroll
      for (int r = 0; r < 4; ++r) acc[mi][ni][r] = 0.f;

  __syncthreads();
  for (int t = 0; t < 16; ++t) {
    int cur = t & 1;
    if (t < 15) {
      int kn = (t + 1) * 64;
      GLD16(&As[cur ^ 1][i0 * 8], &A[(size_t)(bm + r0) * 1024 + kn + s0 * 8]);
      GLD16(&As[cur ^ 1][i1 * 8], &A[(size_t)(bm + r1) * 1024 + kn + s1 * 8]);
      GLD16(&Bs[cur ^ 1][i0 * 8], &BT[(size_t)(bn + r0) * 1024 + kn + s0 * 8]);
      GLD16(&Bs[cur ^ 1][i1 * 8], &BT[(size_t)(bn + r1) * 1024 + kn + s1 * 8]);
    }
#pragma unroll
    for (int kc = 0; kc < 2; ++kc) {
      const int cread = (((kc << 2) + g) ^ x7) * 8;
      short8 a[4], b[2];
#pragma unroll
      for (int mi = 0; mi < 4; ++mi)
        a[mi] = *(const short8*)&As[cur][(wm * 64 + mi * 16 + l15) * 64 + cread];
#pragma unroll
      for (int ni = 0; ni < 2; ++ni)
        b[ni] = *(const short8*)&Bs[cur][(wn * 32 + ni * 16 + l15) * 64 + cread];
#pragma unroll
      for (int mi = 0; mi < 4; ++mi)
#pragma unroll
        for (int ni = 0; ni < 2; ++ni)
          acc[mi][ni] = __builtin_amdgcn_mfma_f32_16x16x32_bf16(a[mi], b[ni], acc[mi][ni], 0, 0, 0);
    }
    __syncthreads();
  }

  float rowsq[4][4];
#pragma unroll
  for (int mi = 0; mi < 4; ++mi)
#pragma unroll
    for (int r = 0; r < 4; ++r) rowsq[mi][r] = 0.f;

#pragma unroll
  for (int ni = 0; ni < 2; ++ni) {
    int n = bn + wn * 32 + ni * 16 + l15;
    float bv = bias[n];
#pragma unroll
    for (int mi = 0; mi < 4; ++mi) {
#pragma unroll
      for (int r = 0; r < 4; ++r) {
        int m = bm + wm * 64 + mi * 16 + 4 * g + r;
        float v = acc[mi][ni][r] + bv;
        if (mode == 0) {
          int b = m >> 10, ll = m & 1023, h = n >> 6, hd = n & 63;
          unsigned short ush = f2bf(v);
          ((unsigned short*)Y)[(((size_t)(b * 16 + h) * 1024) + ll) * 64 + hd] = ush;
          float f = bf2f(ush);
          rowsq[mi][r] = fmaf(f, f, rowsq[mi][r]);
        } else if (mode == 1) {
          int b = m >> 10, ll = m & 1023, h = n >> 6, hd = n & 63;
          int jp = (ll & ~31) | (((ll >> 2) & 3) * 8 + ((ll >> 4) & 1) * 4 + (ll & 3));
          ((unsigned short*)Y)[(((size_t)(b * 16 + h) * 64) + hd) * 1024 + jp] = f2bf(v);
        } else {
          ((float*)Y)[(size_t)m * 1024 + n] = v;
        }
      }
    }
  }

  if (sq != nullptr) {
    float* Sq = (float*)&As[0][0];  // reuse (all compute past final barrier)
#pragma unroll
    for (int mi = 0; mi < 4; ++mi)
#pragma unroll
      for (int r = 0; r < 4; ++r) {
        float s = rowsq[mi][r];
        s += __shfl_xor(s, 1);
        s += __shfl_xor(s, 2);
        s += __shfl_xor(s, 4);
        s += __shfl_xor(s, 8);
        rowsq[mi][r] = s;
      }
    if (l15 == 0) {
#pragma unroll
      for (int mi = 0; mi < 4; ++mi)
#pragma unroll
        for (int r = 0; r < 4; ++r)
          Sq[(wm * 4 + wn) * 64 + mi * 16 + 4 * g + r] = rowsq[mi][r];
    }
    __syncthreads();
    if (tid < 256) {
      int rr = tid & 127, hh = tid >> 7;
      float s = Sq[((rr >> 6) * 4 + 2 * hh) * 64 + (rr & 63)] +
                Sq[((rr >> 6) * 4 + 2 * hh + 1) * 64 + (rr & 63)];
      int m = bm + rr, b = m >> 10, ll = m & 1023;
      int h = (bn >> 6) + hh;
      sq[(size_t)(b * 16 + h) * 1024 + ll] = s;
    }
  }
}

// ---------------------------------------------------------------------------
// 64-cube MFMA GEMM — output projection.
__global__ __launch_bounds__(256) void gemm_st(const unsigned short* __restrict__ A,
                                               const unsigned short* __restrict__ BT,
                                               const float* __restrict__ bias,
                                               float* __restrict__ Y) {
  __shared__ __align__(16) unsigned short As[2][64 * 64];
  __shared__ __align__(16) unsigned short Bs[2][64 * 64];
  int tid = threadIdx.x;
  int w = tid >> 6, l = tid & 63, g = l >> 4, l15 = l & 15;
  int bm = blockIdx.x * 64, bn = blockIdx.y * 64;
  const int arow = w * 16 + l15;
  const int x7 = l15 & 7;

  const int i0s = tid, i1s = 256 + tid;
  const int r0 = i0s >> 3, s0 = (i0s & 7) ^ (r0 & 7);
  const int r1 = i1s >> 3, s1 = (i1s & 7) ^ (r1 & 7);

  GLD16(&As[0][i0s * 8], &A[(size_t)(bm + r0) * 1024 + s0 * 8]);
  GLD16(&As[0][i1s * 8], &A[(size_t)(bm + r1) * 1024 + s1 * 8]);
  GLD16(&Bs[0][i0s * 8], &BT[(size_t)(bn + r0) * 1024 + s0 * 8]);
  GLD16(&Bs[0][i1s * 8], &BT[(size_t)(bn + r1) * 1024 + s1 * 8]);

  f32x4 acc[4];
#pragma unroll
  for (int t = 0; t < 4; ++t)
#pragma unroll
    for (int r = 0; r < 4; ++r) acc[t][r] = 0.f;

  __syncthreads();
  for (int t = 0; t < 16; ++t) {
    int cur = t & 1;
    if (t < 15) {
      int kn = (t + 1) * 64;
      GLD16(&As[cur ^ 1][i0s * 8], &A[(size_t)(bm + r0) * 1024 + kn + s0 * 8]);
      GLD16(&As[cur ^ 1][i1s * 8], &A[(size_t)(bm + r1) * 1024 + kn + s1 * 8]);
      GLD16(&Bs[cur ^ 1][i0s * 8], &BT[(size_t)(bn + r0) * 1024 + kn + s0 * 8]);
      GLD16(&Bs[cur ^ 1][i1s * 8], &BT[(size_t)(bn + r1) * 1024 + kn + s1 * 8]);
    }
#pragma unroll
    for (int kc = 0; kc < 2; ++kc) {
      short8 a = *(const short8*)&As[cur][arow * 64 + ((kc * 4 + g) ^ x7) * 8];
#pragma unroll
      for (int tt = 0; tt < 4; ++tt) {
        short8 b = *(const short8*)&Bs[cur][(tt * 16 + l15) * 64 + ((kc * 4 + g) ^ x7) * 8];
        acc[tt] = __builtin_amdgcn_mfma_f32_16x16x32_bf16(a, b, acc[tt], 0, 0, 0);
      }
    }
    __syncthreads();
  }

#pragma unroll
  for (int t = 0; t < 4; ++t) {
    int n = bn + 16 * t + l15;
    float bv = bias[n];
#pragma unroll
    for (int r = 0; r < 4; ++r) {
      int m = bm + w * 16 + 4 * g + r;
      Y[(size_t)m * 1024 + n] = acc[t][r] + bv;
    }
  }
}

// ---------------------------------------------------------------------------
// colsum: column sums -> rnc = colsum^-0.5. grid (32 bh, 16 jt64), 256 thr.
// 3-buffer counted-vmcnt pipeline; Q streamed in 16 tiles of 64 rows.
__global__ __launch_bounds__(256, 4) void colsum_mfma(const unsigned short* __restrict__ Qb,
                                                      const unsigned short* __restrict__ Kb,
                                                      const float* __restrict__ q2,
                                                      const float* __restrict__ k2,
                                                      float* __restrict__ rnc) {
  __shared__ __align__(16) unsigned short Qd[3][64 * 64];
  __shared__ __align__(16) float q2s[1024];
  int bh = blockIdx.x, jt = blockIdx.y;
  int tid = threadIdx.x, w = tid >> 6, l = tid & 63;
  int g = l >> 4, l15 = l & 15;
  const int x7 = l15 & 7;
  const unsigned short* Qp = Qb + (size_t)bh * 65536;
  const unsigned short* Kp = Kb + (size_t)bh * 65536;
  int j = jt * 64 + w * 16 + l15;

  const int i0s = tid, i1s = 256 + tid;
  const int r0 = i0s >> 3, s0 = (i0s & 7) ^ (r0 & 7);
  const int r1 = i1s >> 3, s1 = (i1s & 7) ^ (r1 & 7);

  // prologue: q2s (1 load) + tiles 0,1 (2 loads each)
  GLD16(&q2s[tid * 4], q2 + (size_t)bh * 1024 + tid * 4);
  GLD16(&Qd[0][i0s * 8], Qp + (size_t)r0 * 64 + s0 * 8);
  GLD16(&Qd[0][i1s * 8], Qp + (size_t)r1 * 64 + s1 * 8);
  GLD16(&Qd[1][i0s * 8], Qp + (size_t)(64 + r0) * 64 + s0 * 8);
  GLD16(&Qd[1][i1s * 8], Qp + (size_t)(64 + r1) * 64 + s1 * 8);

  short8 bk0 = *(const short8*)&Kp[(size_t)j * 64 + 8 * g];
  short8 bk1 = *(const short8*)&Kp[(size_t)j * 64 + 32 + 8 * g];
  float k2j = k2[(size_t)bh * 1024 + j];
  float colacc = 0.f;

  asm volatile("s_waitcnt vmcnt(2)" ::: "memory");  // q2s + tile0 done
  HARD_BARRIER();

  for (int t = 0; t < 16; ++t) {
    int cur = t % 3;
    if (t < 14) {
      int nb = (t + 2) % 3;
      int inx = (t + 2) * 64;
      GLD16(&Qd[nb][i0s * 8], Qp + (size_t)(inx + r0) * 64 + s0 * 8);
      GLD16(&Qd[nb][i1s * 8], Qp + (size_t)(inx + r1) * 64 + s1 * 8);
    }
    MEMFENCE();  // pin prefetch issue before compute/waitcnt
    const unsigned short* Ql = &Qd[cur][0];
#pragma unroll
    for (int tp = 0; tp < 4; ++tp) {
      int rowb = (16 * tp + l15) * 64;
      short8 a0 = *(const short8*)&Ql[rowb + ((g) ^ x7) * 8];
      short8 a1 = *(const short8*)&Ql[rowb + ((4 + g) ^ x7) * 8];
      f32x4 cf;
#pragma unroll
      for (int r = 0; r < 4; ++r) cf[r] = 0.f;
      __builtin_amdgcn_s_setprio(1);
      cf = __builtin_amdgcn_mfma_f32_16x16x32_bf16(a0, bk0, cf, 0, 0, 0);
      cf = __builtin_amdgcn_mfma_f32_16x16x32_bf16(a1, bk1, cf, 0, 0, 0);
      __builtin_amdgcn_s_setprio(0);
      float4 qv = *(const float4*)&q2s[t * 64 + 16 * tp + 4 * g];
      colacc += score_fn(cf[0], qv.x + k2j);
      colacc += score_fn(cf[1], qv.y + k2j);
      colacc += score_fn(cf[2], qv.z + k2j);
      colacc += score_fn(cf[3], qv.w + k2j);
    }
    if (t < 14) {
      asm volatile("s_waitcnt vmcnt(2)" ::: "memory");  // tile t+1 done
    } else {
      asm volatile("s_waitcnt vmcnt(0)" ::: "memory");
    }
    HARD_BARRIER();
  }
  colacc += __shfl_xor(colacc, 16);
  colacc += __shfl_xor(colacc, 32);
  if (l < 16) rnc[(size_t)bh * 1024 + jt * 64 + w * 16 + l] = __builtin_amdgcn_rsqf(colacc);
}

// ---------------------------------------------------------------------------
// attn (swapped QK, register P): grid (32 bh, 16 qt64), 256 thr.
// 3-buffer counted-vmcnt pipeline; K,V streamed in 16 tiles of 64 cols.
__global__ __launch_bounds__(256, 2) void attn_mfma(const unsigned short* __restrict__ Qb,
                                                    const unsigned short* __restrict__ Kb,
                                                    const unsigned short* __restrict__ VTp,
                                                    const float* __restrict__ q2,
                                                    const float* __restrict__ k2,
                                                    const float* __restrict__ rnc,
                                                    unsigned short* __restrict__ AO) {
  __shared__ __align__(16) unsigned short Kd[3][64 * 64];
  __shared__ __align__(16) unsigned short Vd[3][64 * 64];
  __shared__ __align__(16) float k2s[1024];
  __shared__ __align__(16) float rns[1024];
  int bh = blockIdx.x;
  int tid = threadIdx.x, w = tid >> 6, l = tid & 63;
  int g = l >> 4, l15 = l & 15;
  const int x7 = l15 & 7;
  int it0 = blockIdx.y * 64 + w * 16;
  const unsigned short* Qp = Qb + (size_t)bh * 65536;
  const unsigned short* Kp = Kb + (size_t)bh * 65536;
  const unsigned short* Vp = VTp + (size_t)bh * 65536;
  int b = bh >> 4, h = bh & 15;

  const int i0s = tid, i1s = 256 + tid;
  const int r0 = i0s >> 3, s0 = (i0s & 7) ^ (r0 & 7);
  const int r1 = i1s >> 3, s1 = (i1s & 7) ^ (r1 & 7);

  // prologue: misc (2 loads) + tiles 0,1 (4 loads each)
  GLD16(&k2s[tid * 4], k2 + (size_t)bh * 1024 + tid * 4);
  GLD16(&rns[tid * 4], rnc + (size_t)bh * 1024 + tid * 4);
  GLD16(&Kd[0][i0s * 8], Kp + (size_t)r0 * 64 + s0 * 8);
  GLD16(&Kd[0][i1s * 8], Kp + (size_t)r1 * 64 + s1 * 8);
  GLD16(&Vd[0][i0s * 8], Vp + (size_t)r0 * 1024 + s0 * 8);
  GLD16(&Vd[0][i1s * 8], Vp + (size_t)r1 * 1024 + s1 * 8);
  GLD16(&Kd[1][i0s * 8], Kp + (size_t)(64 + r0) * 64 + s0 * 8);
  GLD16(&Kd[1][i1s * 8], Kp + (size_t)(64 + r1) * 64 + s1 * 8);
  GLD16(&Vd[1][i0s * 8], Vp + (size_t)r0 * 1024 + 64 + s0 * 8);
  GLD16(&Vd[1][i1s * 8], Vp + (size_t)r1 * 1024 + 64 + s1 * 8);

  short8 bq0 = *(const short8*)&Qp[(size_t)(it0 + l15) * 64 + 8 * g];
  short8 bq1 = *(const short8*)&Qp[(size_t)(it0 + l15) * 64 + 32 + 8 * g];
  float q2l = q2[(size_t)bh * 1024 + it0 + l15];

  f32x4 o[4];
#pragma unroll
  for (int t = 0; t < 4; ++t)
#pragma unroll
    for (int r = 0; r < 4; ++r) o[t][r] = 0.f;
  float dacc = 0.f;

  asm volatile("s_waitcnt vmcnt(4)" ::: "memory");  // misc + tile0 done
  HARD_BARRIER();

  for (int t = 0; t < 16; ++t) {
    int cur = t % 3;
    if (t < 14) {
      int nb = (t + 2) % 3;
      int j0n = (t + 2) * 64;
      GLD16(&Kd[nb][i0s * 8], Kp + (size_t)(j0n + r0) * 64 + s0 * 8);
      GLD16(&Kd[nb][i1s * 8], Kp + (size_t)(j0n + r1) * 64 + s1 * 8);
      GLD16(&Vd[nb][i0s * 8], Vp + (size_t)r0 * 1024 + j0n + s0 * 8);
      GLD16(&Vd[nb][i1s * 8], Vp + (size_t)r1 * 1024 + j0n + s1 * 8);
    }
    MEMFENCE();  // pin prefetch issue before compute/waitcnt
    const unsigned short* Kl = &Kd[cur][0];
    const unsigned short* Vl = &Vd[cur][0];
    int j0 = t * 64;
    float sc[16];
#pragma unroll
    for (int tp = 0; tp < 4; ++tp) {
      int rowb = (16 * tp + l15) * 64;
      short8 a0 = *(const short8*)&Kl[rowb + ((g) ^ x7) * 8];
      short8 a1 = *(const short8*)&Kl[rowb + ((4 + g) ^ x7) * 8];
      f32x4 cf;
#pragma unroll
      for (int r = 0; r < 4; ++r) cf[r] = 0.f;
      __builtin_amdgcn_s_setprio(1);
      cf = __builtin_amdgcn_mfma_f32_16x16x32_bf16(a0, bq0, cf, 0, 0, 0);
      cf = __builtin_amdgcn_mfma_f32_16x16x32_bf16(a1, bq1, cf, 0, 0, 0);
      __builtin_amdgcn_s_setprio(0);
      float4 kv = *(const float4*)&k2s[j0 + 16 * tp + 4 * g];
      float4 rv = *(const float4*)&rns[j0 + 16 * tp + 4 * g];
      sc[tp * 4 + 0] = score_fn(cf[0], q2l + kv.x) * rv.x;
      sc[tp * 4 + 1] = score_fn(cf[1], q2l + kv.y) * rv.y;
      sc[tp * 4 + 2] = score_fn(cf[2], q2l + kv.z) * rv.z;
      sc[tp * 4 + 3] = score_fn(cf[3], q2l + kv.w) * rv.w;
    }
#pragma unroll
    for (int i = 0; i < 16; ++i) dacc += sc[i];
    int pi0[4], pi1[4];
    pi0[0] = (int)cvtpk(sc[0], sc[1]);
    pi0[1] = (int)cvtpk(sc[2], sc[3]);
    pi0[2] = (int)cvtpk(sc[4], sc[5]);
    pi0[3] = (int)cvtpk(sc[6], sc[7]);
    pi1[0] = (int)cvtpk(sc[8], sc[9]);
    pi1[1] = (int)cvtpk(sc[10], sc[11]);
    pi1[2] = (int)cvtpk(sc[12], sc[13]);
    pi1[3] = (int)cvtpk(sc[14], sc[15]);
    short8 pa0 = *(short8*)pi0;
    short8 pa1 = *(short8*)pi1;
#pragma unroll
    for (int t5 = 0; t5 < 4; ++t5) {
      int rowb = (16 * t5 + l15) * 64;
      short8 v0 = *(const short8*)&Vl[rowb + ((g) ^ x7) * 8];
      short8 v1 = *(const short8*)&Vl[rowb + ((4 + g) ^ x7) * 8];
      __builtin_amdgcn_s_setprio(1);
      o[t5] = __builtin_amdgcn_mfma_f32_16x16x32_bf16(pa0, v0, o[t5], 0, 0, 0);
      o[t5] = __builtin_amdgcn_mfma_f32_16x16x32_bf16(pa1, v1, o[t5], 0, 0, 0);
      __builtin_amdgcn_s_setprio(0);
    }
    if (t < 14) {
      asm volatile("s_waitcnt vmcnt(4)" ::: "memory");  // tile t+1 done
    } else {
      asm volatile("s_waitcnt vmcnt(0)" ::: "memory");
    }
    HARD_BARRIER();
  }

  dacc += __shfl_xor(dacc, 16);
  dacc += __shfl_xor(dacc, 32);
  float dv[4];
#pragma unroll
  for (int r = 0; r < 4; ++r) dv[r] = __shfl(dacc, 4 * g + r);

#pragma unroll
  for (int t = 0; t < 4; ++t) {
#pragma unroll
    for (int r = 0; r < 4; ++r) {
      int m = b * 1024 + it0 + 4 * g + r;
      int n = h * 64 + t * 16 + l15;
      AO[(size_t)m * 1024 + n] = f2bf(o[t][r] / dv[r]);
    }
  }
}

// ---------------------------------------------------------------------------
extern "C" void kernel_launch(void* const* d_in, const int* in_sizes, int n_in,
                              void* d_out, int out_size, void* d_ws, size_t ws_size,
                              hipStream_t stream) {
  const float* x  = (const float*)d_in[0];
  const float* WQ = (const float*)d_in[1];
  const float* bQ = (const float*)d_in[2];
  const float* WK = (const float*)d_in[3];
  const float* bK = (const float*)d_in[4];
  const float* WV = (const float*)d_in[5];
  const float* bV = (const float*)d_in[6];
  const float* WO = (const float*)d_in[7];
  const float* bO = (const float*)d_in[8];

  char* base = (char*)d_ws;
  unsigned short* xb  = (unsigned short*)(base);
  unsigned short* WQT = (unsigned short*)(base + (4u  << 20));
  unsigned short* WKT = (unsigned short*)(base + (6u  << 20));
  unsigned short* WVT = (unsigned short*)(base + (8u  << 20));
  unsigned short* WOT = (unsigned short*)(base + (10u << 20));
  unsigned short* Qb  = (unsigned short*)(base + (12u << 20));
  unsigned short* Kb  = (unsigned short*)(base + (16u << 20));
  unsigned short* VTp = (unsigned short*)(base + (20u << 20));
  unsigned short* AOb = (unsigned short*)(base + (24u << 20));
  float* q2  = (float*)(base + (28u << 20));
  float* k2  = (float*)(base + (28u << 20) + (128u << 10));
  float* rnc = (float*)(base + (28u << 20) + (256u << 10));

  prep<<<6144, 256, 0, stream>>>(x, xb, WQ, WK, WV, WO, WQT, WKT, WVT, WOT);

  gemm128k64<<<dim3(16, 8, 3), 512, 0, stream>>>(xb, WQT, WKT, WVT, bQ, bK, bV,
                                                 Qb, Kb, VTp, q2, k2, nullptr,
                                                 0, 0, 1);

  colsum_mfma<<<dim3(32, 16), 256, 0, stream>>>(Qb, Kb, q2, k2, rnc);
  attn_mfma<<<dim3(32, 16), 256, 0, stream>>>(Qb, Kb, VTp, q2, k2, rnc, AOb);

  gemm_st<<<dim3(32, 16), 256, 0, stream>>>(AOb, WOT, bO, (float*)d_out);
}

// Round 15
// 97.494 us; speedup vs baseline: 1.0623x; 1.0081x over previous
//
#include <hip/hip_runtime.h>
#include <math.h>

// B=2, L=1024, D=1024, H=16, HD=64.
// probs_ij = s_ij*nc_j^-0.5 / sum_j(s_ij*nc_j^-0.5)   (N_R^-0.5 cancels)
// s_ij = (1 + dist_ij/64)^(-65.5), dist from bf16-rounded Q,K.
// r15 = r14 base + QKV gemm reshaped: BM128xBN64xBK32, 768 blocks (3/CU).

typedef __attribute__((ext_vector_type(8))) short short8;
typedef __attribute__((ext_vector_type(4))) float f32x4;

__device__ inline unsigned short f2bf(float f) {
  unsigned int u = __float_as_uint(f);
  unsigned int r = (u + 0x7FFFu + ((u >> 16) & 1u)) >> 16;
  return (unsigned short)r;
}
__device__ inline float bf2f(unsigned short s) {
  return __uint_as_float(((unsigned int)s) << 16);
}
__device__ inline float score_fn(float dot, float sq) {
  float d2 = fmaxf(fmaf(-2.f, dot, sq), 1e-12f);
  float sd = __builtin_amdgcn_sqrtf(d2);
  float lg = __builtin_amdgcn_logf(fmaf(sd, 0.015625f, 1.0f));  // log2(1+dist/64)
  return __builtin_amdgcn_exp2f(-65.5f * lg);
}
__device__ inline unsigned int cvtpk(float lo, float hi) {
  unsigned int r;
  asm("v_cvt_pk_bf16_f32 %0, %1, %2" : "=v"(r) : "v"(lo), "v"(hi));
  return r;
}
#define GLD16(lptr, gptr)                                                      \
  __builtin_amdgcn_global_load_lds(                                            \
      (const __attribute__((address_space(1))) void*)(gptr),                   \
      (__attribute__((address_space(3))) void*)(lptr), 16, 0, 0)
#define MEMFENCE() asm volatile("" ::: "memory")
#define HARD_BARRIER()                 \
  do {                                 \
    __builtin_amdgcn_s_barrier();      \
    MEMFENCE();                        \
  } while (0)

// ---------------------------------------------------------------------------
// prep: blocks [0,2048) = x f32->bf16; blocks [2048,6144) = 4 weight transposes
__global__ __launch_bounds__(256) void prep(const float* __restrict__ x,
                                            unsigned short* __restrict__ xb,
                                            const float* __restrict__ W0,
                                            const float* __restrict__ W1,
                                            const float* __restrict__ W2,
                                            const float* __restrict__ W3,
                                            unsigned short* __restrict__ T0,
                                            unsigned short* __restrict__ T1,
                                            unsigned short* __restrict__ T2,
                                            unsigned short* __restrict__ T3) {
  __shared__ float T[32][33];
  int bx = blockIdx.x;
  if (bx < 2048) {
    int i = bx * 256 + threadIdx.x;
    float4 v = ((const float4*)x)[i];
    xb[4 * i + 0] = f2bf(v.x);
    xb[4 * i + 1] = f2bf(v.y);
    xb[4 * i + 2] = f2bf(v.z);
    xb[4 * i + 3] = f2bf(v.w);
    return;
  }
  int idx = bx - 2048;
  int z = idx >> 10, rem = idx & 1023;
  const float* W = z == 0 ? W0 : z == 1 ? W1 : z == 2 ? W2 : W3;
  unsigned short* WT = z == 0 ? T0 : z == 1 ? T1 : z == 2 ? T2 : T3;
  int k0 = (rem >> 5) * 32, n0 = (rem & 31) * 32;
  int c = threadIdx.x & 31, r8 = threadIdx.x >> 5;
#pragma unroll
  for (int it = 0; it < 4; ++it) {
    int rr = r8 + it * 8;
    T[rr][c] = W[(size_t)(k0 + rr) * 1024 + n0 + c];
  }
  __syncthreads();
#pragma unroll
  for (int it = 0; it < 4; ++it) {
    int rr = r8 + it * 8;
    WT[(size_t)(n0 + rr) * 1024 + k0 + c] = f2bf(T[c][rr]);
  }
}

// ---------------------------------------------------------------------------
// QKV GEMM: BM=128, BN=64, BK=32, 256 thr / 4 waves (2x2), wave-tile 64x32.
// grid (16,16,3) = 768 blocks -> 3 blocks/CU, 12 waves/CU. LDS 24KB.
// mode 0 emits per-row sum-of-squares of the bf16 output (q2/k2); BN=64 means
// each block covers exactly one head's column block.
__global__ __launch_bounds__(256, 3) void gemm_qkv(const unsigned short* __restrict__ A,
                                                   const unsigned short* __restrict__ B0,
                                                   const unsigned short* __restrict__ B1,
                                                   const unsigned short* __restrict__ B2,
                                                   const float* __restrict__ c0,
                                                   const float* __restrict__ c1,
                                                   const float* __restrict__ c2,
                                                   void* __restrict__ Y0,
                                                   void* __restrict__ Y1,
                                                   void* __restrict__ Y2,
                                                   float* __restrict__ sq0,
                                                   float* __restrict__ sq1,
                                                   float* __restrict__ sq2,
                                                   int m0, int m1, int m2) {
  int z = blockIdx.z;
  const unsigned short* BT = z == 0 ? B0 : z == 1 ? B1 : B2;
  const float* bias = z == 0 ? c0 : z == 1 ? c1 : c2;
  void* Y = z == 0 ? Y0 : z == 1 ? Y1 : Y2;
  float* sq = z == 0 ? sq0 : z == 1 ? sq1 : sq2;
  int mode = z == 0 ? m0 : z == 1 ? m1 : m2;

  __shared__ __align__(16) unsigned short As[2][128 * 32];  // 8KB each
  __shared__ __align__(16) unsigned short Bs[2][64 * 32];   // 4KB each
  int tid = threadIdx.x;
  int w = tid >> 6, l = tid & 63, g = l >> 4, l15 = l & 15;
  int wm = w >> 1, wn = w & 1;
  int bm = blockIdx.x * 128, bn = blockIdx.y * 64;

  // A staging: 512 chunks (2/thread); B staging: 256 chunks (1/thread).
  // slot-swizzle: src chunk = slot ^ (row&3) ^ ((row>>2)&3)
  const int cA0 = tid, cA1 = tid + 256;
  const int rA0 = cA0 >> 2, sA0 = (cA0 & 3) ^ (rA0 & 3) ^ ((rA0 >> 2) & 3);
  const int rA1 = cA1 >> 2, sA1 = (cA1 & 3) ^ (rA1 & 3) ^ ((rA1 >> 2) & 3);
  const int rB0 = tid >> 2, sB0 = (tid & 3) ^ (rB0 & 3) ^ ((rB0 >> 2) & 3);

  // prologue: stage k-tile 0
  GLD16(&As[0][cA0 * 8], &A[(size_t)(bm + rA0) * 1024 + sA0 * 8]);
  GLD16(&As[0][cA1 * 8], &A[(size_t)(bm + rA1) * 1024 + sA1 * 8]);
  GLD16(&Bs[0][tid * 8], &BT[(size_t)(bn + rB0) * 1024 + sB0 * 8]);

  f32x4 acc[4][2];
#pragma unroll
  for (int mi = 0; mi < 4; ++mi)
#pragma unroll
    for (int ni = 0; ni < 2; ++ni)
#pragma unroll
      for (int r = 0; r < 4; ++r) acc[mi][ni][r] = 0.f;

  // per-lane fragment read slots (row-dependent XOR)
  int arow[4], aslot[4], brow[2], bslot[2];
#pragma unroll
  for (int mi = 0; mi < 4; ++mi) {
    arow[mi] = wm * 64 + mi * 16 + l15;
    aslot[mi] = g ^ (arow[mi] & 3) ^ ((arow[mi] >> 2) & 3);
  }
#pragma unroll
  for (int ni = 0; ni < 2; ++ni) {
    brow[ni] = wn * 32 + ni * 16 + l15;
    bslot[ni] = g ^ (brow[ni] & 3) ^ ((brow[ni] >> 2) & 3);
  }

  __syncthreads();
  for (int t = 0; t < 32; ++t) {
    int cur = t & 1;
    if (t < 31) {
      int kn = (t + 1) * 32;
      GLD16(&As[cur ^ 1][cA0 * 8], &A[(size_t)(bm + rA0) * 1024 + kn + sA0 * 8]);
      GLD16(&As[cur ^ 1][cA1 * 8], &A[(size_t)(bm + rA1) * 1024 + kn + sA1 * 8]);
      GLD16(&Bs[cur ^ 1][tid * 8], &BT[(size_t)(bn + rB0) * 1024 + kn + sB0 * 8]);
    }
    short8 a[4], b[2];
#pragma unroll
    for (int mi = 0; mi < 4; ++mi)
      a[mi] = *(const short8*)&As[cur][arow[mi] * 32 + aslot[mi] * 8];
#pragma unroll
    for (int ni = 0; ni < 2; ++ni)
      b[ni] = *(const short8*)&Bs[cur][brow[ni] * 32 + bslot[ni] * 8];
#pragma unroll
    for (int mi = 0; mi < 4; ++mi)
#pragma unroll
      for (int ni = 0; ni < 2; ++ni)
        acc[mi][ni] = __builtin_amdgcn_mfma_f32_16x16x32_bf16(a[mi], b[ni], acc[mi][ni], 0, 0, 0);
    __syncthreads();
  }

  float rowsq[4][4];
#pragma unroll
  for (int mi = 0; mi < 4; ++mi)
#pragma unroll
    for (int r = 0; r < 4; ++r) rowsq[mi][r] = 0.f;

#pragma unroll
  for (int ni = 0; ni < 2; ++ni) {
    int n = bn + wn * 32 + ni * 16 + l15;
    float bv = bias[n];
#pragma unroll
    for (int mi = 0; mi < 4; ++mi) {
#pragma unroll
      for (int r = 0; r < 4; ++r) {
        int m = bm + wm * 64 + mi * 16 + 4 * g + r;
        float v = acc[mi][ni][r] + bv;
        if (mode == 0) {
          int b = m >> 10, ll = m & 1023, h = n >> 6, hd = n & 63;
          unsigned short ush = f2bf(v);
          ((unsigned short*)Y)[(((size_t)(b * 16 + h) * 1024) + ll) * 64 + hd] = ush;
          float f = bf2f(ush);
          rowsq[mi][r] = fmaf(f, f, rowsq[mi][r]);
        } else if (mode == 1) {
          int b = m >> 10, ll = m & 1023, h = n >> 6, hd = n & 63;
          int jp = (ll & ~31) | (((ll >> 2) & 3) * 8 + ((ll >> 4) & 1) * 4 + (ll & 3));
          ((unsigned short*)Y)[(((size_t)(b * 16 + h) * 64) + hd) * 1024 + jp] = f2bf(v);
        } else {
          ((float*)Y)[(size_t)m * 1024 + n] = v;
        }
      }
    }
  }

  if (sq != nullptr) {
    float* Sq = (float*)&As[0][0];  // 2x128 floats, reuse after final barrier
#pragma unroll
    for (int mi = 0; mi < 4; ++mi)
#pragma unroll
      for (int r = 0; r < 4; ++r) {
        float s = rowsq[mi][r];
        s += __shfl_xor(s, 1);
        s += __shfl_xor(s, 2);
        s += __shfl_xor(s, 4);
        s += __shfl_xor(s, 8);
        rowsq[mi][r] = s;  // sum over this wave's 32 cols for row mi*16+4g+r
      }
    if (l15 == 0) {
#pragma unroll
      for (int mi = 0; mi < 4; ++mi)
#pragma unroll
        for (int r = 0; r < 4; ++r)
          Sq[wn * 128 + wm * 64 + mi * 16 + 4 * g + r] = rowsq[mi][r];
    }
    __syncthreads();
    if (tid < 128) {
      float s = Sq[tid] + Sq[128 + tid];
      int m = bm + tid, b = m >> 10, ll = m & 1023;
      int h = bn >> 6;
      sq[(size_t)(b * 16 + h) * 1024 + ll] = s;
    }
  }
}

// ---------------------------------------------------------------------------
// 64-cube MFMA GEMM — output projection.
__global__ __launch_bounds__(256) void gemm_st(const unsigned short* __restrict__ A,
                                               const unsigned short* __restrict__ BT,
                                               const float* __restrict__ bias,
                                               float* __restrict__ Y) {
  __shared__ __align__(16) unsigned short As[2][64 * 64];
  __shared__ __align__(16) unsigned short Bs[2][64 * 64];
  int tid = threadIdx.x;
  int w = tid >> 6, l = tid & 63, g = l >> 4, l15 = l & 15;
  int bm = blockIdx.x * 64, bn = blockIdx.y * 64;
  const int arow = w * 16 + l15;
  const int x7 = l15 & 7;

  const int i0s = tid, i1s = 256 + tid;
  const int r0 = i0s >> 3, s0 = (i0s & 7) ^ (r0 & 7);
  const int r1 = i1s >> 3, s1 = (i1s & 7) ^ (r1 & 7);

  GLD16(&As[0][i0s * 8], &A[(size_t)(bm + r0) * 1024 + s0 * 8]);
  GLD16(&As[0][i1s * 8], &A[(size_t)(bm + r1) * 1024 + s1 * 8]);
  GLD16(&Bs[0][i0s * 8], &BT[(size_t)(bn + r0) * 1024 + s0 * 8]);
  GLD16(&Bs[0][i1s * 8], &BT[(size_t)(bn + r1) * 1024 + s1 * 8]);

  f32x4 acc[4];
#pragma unroll
  for (int t = 0; t < 4; ++t)
#pragma unroll
    for (int r = 0; r < 4; ++r) acc[t][r] = 0.f;

  __syncthreads();
  for (int t = 0; t < 16; ++t) {
    int cur = t & 1;
    if (t < 15) {
      int kn = (t + 1) * 64;
      GLD16(&As[cur ^ 1][i0s * 8], &A[(size_t)(bm + r0) * 1024 + kn + s0 * 8]);
      GLD16(&As[cur ^ 1][i1s * 8], &A[(size_t)(bm + r1) * 1024 + kn + s1 * 8]);
      GLD16(&Bs[cur ^ 1][i0s * 8], &BT[(size_t)(bn + r0) * 1024 + kn + s0 * 8]);
      GLD16(&Bs[cur ^ 1][i1s * 8], &BT[(size_t)(bn + r1) * 1024 + kn + s1 * 8]);
    }
#pragma unroll
    for (int kc = 0; kc < 2; ++kc) {
      short8 a = *(const short8*)&As[cur][arow * 64 + ((kc * 4 + g) ^ x7) * 8];
#pragma unroll
      for (int tt = 0; tt < 4; ++tt) {
        short8 b = *(const short8*)&Bs[cur][(tt * 16 + l15) * 64 + ((kc * 4 + g) ^ x7) * 8];
        acc[tt] = __builtin_amdgcn_mfma_f32_16x16x32_bf16(a, b, acc[tt], 0, 0, 0);
      }
    }
    __syncthreads();
  }

#pragma unroll
  for (int t = 0; t < 4; ++t) {
    int n = bn + 16 * t + l15;
    float bv = bias[n];
#pragma unroll
    for (int r = 0; r < 4; ++r) {
      int m = bm + w * 16 + 4 * g + r;
      Y[(size_t)m * 1024 + n] = acc[t][r] + bv;
    }
  }
}

// ---------------------------------------------------------------------------
// colsum: column sums -> rnc = colsum^-0.5. grid (32 bh, 16 jt64), 256 thr.
// 3-buffer counted-vmcnt pipeline; Q streamed in 16 tiles of 64 rows.
__global__ __launch_bounds__(256, 4) void colsum_mfma(const unsigned short* __restrict__ Qb,
                                                      const unsigned short* __restrict__ Kb,
                                                      const float* __restrict__ q2,
                                                      const float* __restrict__ k2,
                                                      float* __restrict__ rnc) {
  __shared__ __align__(16) unsigned short Qd[3][64 * 64];
  __shared__ __align__(16) float q2s[1024];
  int bh = blockIdx.x, jt = blockIdx.y;
  int tid = threadIdx.x, w = tid >> 6, l = tid & 63;
  int g = l >> 4, l15 = l & 15;
  const int x7 = l15 & 7;
  const unsigned short* Qp = Qb + (size_t)bh * 65536;
  const unsigned short* Kp = Kb + (size_t)bh * 65536;
  int j = jt * 64 + w * 16 + l15;

  const int i0s = tid, i1s = 256 + tid;
  const int r0 = i0s >> 3, s0 = (i0s & 7) ^ (r0 & 7);
  const int r1 = i1s >> 3, s1 = (i1s & 7) ^ (r1 & 7);

  GLD16(&q2s[tid * 4], q2 + (size_t)bh * 1024 + tid * 4);
  GLD16(&Qd[0][i0s * 8], Qp + (size_t)r0 * 64 + s0 * 8);
  GLD16(&Qd[0][i1s * 8], Qp + (size_t)r1 * 64 + s1 * 8);
  GLD16(&Qd[1][i0s * 8], Qp + (size_t)(64 + r0) * 64 + s0 * 8);
  GLD16(&Qd[1][i1s * 8], Qp + (size_t)(64 + r1) * 64 + s1 * 8);

  short8 bk0 = *(const short8*)&Kp[(size_t)j * 64 + 8 * g];
  short8 bk1 = *(const short8*)&Kp[(size_t)j * 64 + 32 + 8 * g];
  float k2j = k2[(size_t)bh * 1024 + j];
  float colacc = 0.f;

  asm volatile("s_waitcnt vmcnt(2)" ::: "memory");
  HARD_BARRIER();

  for (int t = 0; t < 16; ++t) {
    int cur = t % 3;
    if (t < 14) {
      int nb = (t + 2) % 3;
      int inx = (t + 2) * 64;
      GLD16(&Qd[nb][i0s * 8], Qp + (size_t)(inx + r0) * 64 + s0 * 8);
      GLD16(&Qd[nb][i1s * 8], Qp + (size_t)(inx + r1) * 64 + s1 * 8);
    }
    MEMFENCE();
    const unsigned short* Ql = &Qd[cur][0];
#pragma unroll
    for (int tp = 0; tp < 4; ++tp) {
      int rowb = (16 * tp + l15) * 64;
      short8 a0 = *(const short8*)&Ql[rowb + ((g) ^ x7) * 8];
      short8 a1 = *(const short8*)&Ql[rowb + ((4 + g) ^ x7) * 8];
      f32x4 cf;
#pragma unroll
      for (int r = 0; r < 4; ++r) cf[r] = 0.f;
      __builtin_amdgcn_s_setprio(1);
      cf = __builtin_amdgcn_mfma_f32_16x16x32_bf16(a0, bk0, cf, 0, 0, 0);
      cf = __builtin_amdgcn_mfma_f32_16x16x32_bf16(a1, bk1, cf, 0, 0, 0);
      __builtin_amdgcn_s_setprio(0);
      float4 qv = *(const float4*)&q2s[t * 64 + 16 * tp + 4 * g];
      colacc += score_fn(cf[0], qv.x + k2j);
      colacc += score_fn(cf[1], qv.y + k2j);
      colacc += score_fn(cf[2], qv.z + k2j);
      colacc += score_fn(cf[3], qv.w + k2j);
    }
    if (t < 14) {
      asm volatile("s_waitcnt vmcnt(2)" ::: "memory");
    } else {
      asm volatile("s_waitcnt vmcnt(0)" ::: "memory");
    }
    HARD_BARRIER();
  }
  colacc += __shfl_xor(colacc, 16);
  colacc += __shfl_xor(colacc, 32);
  if (l < 16) rnc[(size_t)bh * 1024 + jt * 64 + w * 16 + l] = __builtin_amdgcn_rsqf(colacc);
}

// ---------------------------------------------------------------------------
// attn (swapped QK, register P): grid (32 bh, 16 qt64), 256 thr.
// 3-buffer counted-vmcnt pipeline; K,V streamed in 16 tiles of 64 cols.
__global__ __launch_bounds__(256, 2) void attn_mfma(const unsigned short* __restrict__ Qb,
                                                    const unsigned short* __restrict__ Kb,
                                                    const unsigned short* __restrict__ VTp,
                                                    const float* __restrict__ q2,
                                                    const float* __restrict__ k2,
                                                    const float* __restrict__ rnc,
                                                    unsigned short* __restrict__ AO) {
  __shared__ __align__(16) unsigned short Kd[3][64 * 64];
  __shared__ __align__(16) unsigned short Vd[3][64 * 64];
  __shared__ __align__(16) float k2s[1024];
  __shared__ __align__(16) float rns[1024];
  int bh = blockIdx.x;
  int tid = threadIdx.x, w = tid >> 6, l = tid & 63;
  int g = l >> 4, l15 = l & 15;
  const int x7 = l15 & 7;
  int it0 = blockIdx.y * 64 + w * 16;
  const unsigned short* Qp = Qb + (size_t)bh * 65536;
  const unsigned short* Kp = Kb + (size_t)bh * 65536;
  const unsigned short* Vp = VTp + (size_t)bh * 65536;
  int b = bh >> 4, h = bh & 15;

  const int i0s = tid, i1s = 256 + tid;
  const int r0 = i0s >> 3, s0 = (i0s & 7) ^ (r0 & 7);
  const int r1 = i1s >> 3, s1 = (i1s & 7) ^ (r1 & 7);

  GLD16(&k2s[tid * 4], k2 + (size_t)bh * 1024 + tid * 4);
  GLD16(&rns[tid * 4], rnc + (size_t)bh * 1024 + tid * 4);
  GLD16(&Kd[0][i0s * 8], Kp + (size_t)r0 * 64 + s0 * 8);
  GLD16(&Kd[0][i1s * 8], Kp + (size_t)r1 * 64 + s1 * 8);
  GLD16(&Vd[0][i0s * 8], Vp + (size_t)r0 * 1024 + s0 * 8);
  GLD16(&Vd[0][i1s * 8], Vp + (size_t)r1 * 1024 + s1 * 8);
  GLD16(&Kd[1][i0s * 8], Kp + (size_t)(64 + r0) * 64 + s0 * 8);
  GLD16(&Kd[1][i1s * 8], Kp + (size_t)(64 + r1) * 64 + s1 * 8);
  GLD16(&Vd[1][i0s * 8], Vp + (size_t)r0 * 1024 + 64 + s0 * 8);
  GLD16(&Vd[1][i1s * 8], Vp + (size_t)r1 * 1024 + 64 + s1 * 8);

  short8 bq0 = *(const short8*)&Qp[(size_t)(it0 + l15) * 64 + 8 * g];
  short8 bq1 = *(const short8*)&Qp[(size_t)(it0 + l15) * 64 + 32 + 8 * g];
  float q2l = q2[(size_t)bh * 1024 + it0 + l15];

  f32x4 o[4];
#pragma unroll
  for (int t = 0; t < 4; ++t)
#pragma unroll
    for (int r = 0; r < 4; ++r) o[t][r] = 0.f;
  float dacc = 0.f;

  asm volatile("s_waitcnt vmcnt(4)" ::: "memory");
  HARD_BARRIER();

  for (int t = 0; t < 16; ++t) {
    int cur = t % 3;
    if (t < 14) {
      int nb = (t + 2) % 3;
      int j0n = (t + 2) * 64;
      GLD16(&Kd[nb][i0s * 8], Kp + (size_t)(j0n + r0) * 64 + s0 * 8);
      GLD16(&Kd[nb][i1s * 8], Kp + (size_t)(j0n + r1) * 64 + s1 * 8);
      GLD16(&Vd[nb][i0s * 8], Vp + (size_t)r0 * 1024 + j0n + s0 * 8);
      GLD16(&Vd[nb][i1s * 8], Vp + (size_t)r1 * 1024 + j0n + s1 * 8);
    }
    MEMFENCE();
    const unsigned short* Kl = &Kd[cur][0];
    const unsigned short* Vl = &Vd[cur][0];
    int j0 = t * 64;
    float sc[16];
#pragma unroll
    for (int tp = 0; tp < 4; ++tp) {
      int rowb = (16 * tp + l15) * 64;
      short8 a0 = *(const short8*)&Kl[rowb + ((g) ^ x7) * 8];
      short8 a1 = *(const short8*)&Kl[rowb + ((4 + g) ^ x7) * 8];
      f32x4 cf;
#pragma unroll
      for (int r = 0; r < 4; ++r) cf[r] = 0.f;
      __builtin_amdgcn_s_setprio(1);
      cf = __builtin_amdgcn_mfma_f32_16x16x32_bf16(a0, bq0, cf, 0, 0, 0);
      cf = __builtin_amdgcn_mfma_f32_16x16x32_bf16(a1, bq1, cf, 0, 0, 0);
      __builtin_amdgcn_s_setprio(0);
      float4 kv = *(const float4*)&k2s[j0 + 16 * tp + 4 * g];
      float4 rv = *(const float4*)&rns[j0 + 16 * tp + 4 * g];
      sc[tp * 4 + 0] = score_fn(cf[0], q2l + kv.x) * rv.x;
      sc[tp * 4 + 1] = score_fn(cf[1], q2l + kv.y) * rv.y;
      sc[tp * 4 + 2] = score_fn(cf[2], q2l + kv.z) * rv.z;
      sc[tp * 4 + 3] = score_fn(cf[3], q2l + kv.w) * rv.w;
    }
#pragma unroll
    for (int i = 0; i < 16; ++i) dacc += sc[i];
    int pi0[4], pi1[4];
    pi0[0] = (int)cvtpk(sc[0], sc[1]);
    pi0[1] = (int)cvtpk(sc[2], sc[3]);
    pi0[2] = (int)cvtpk(sc[4], sc[5]);
    pi0[3] = (int)cvtpk(sc[6], sc[7]);
    pi1[0] = (int)cvtpk(sc[8], sc[9]);
    pi1[1] = (int)cvtpk(sc[10], sc[11]);
    pi1[2] = (int)cvtpk(sc[12], sc[13]);
    pi1[3] = (int)cvtpk(sc[14], sc[15]);
    short8 pa0 = *(short8*)pi0;
    short8 pa1 = *(short8*)pi1;
#pragma unroll
    for (int t5 = 0; t5 < 4; ++t5) {
      int rowb = (16 * t5 + l15) * 64;
      short8 v0 = *(const short8*)&Vl[rowb + ((g) ^ x7) * 8];
      short8 v1 = *(const short8*)&Vl[rowb + ((4 + g) ^ x7) * 8];
      __builtin_amdgcn_s_setprio(1);
      o[t5] = __builtin_amdgcn_mfma_f32_16x16x32_bf16(pa0, v0, o[t5], 0, 0, 0);
      o[t5] = __builtin_amdgcn_mfma_f32_16x16x32_bf16(pa1, v1, o[t5], 0, 0, 0);
      __builtin_amdgcn_s_setprio(0);
    }
    if (t < 14) {
      asm volatile("s_waitcnt vmcnt(4)" ::: "memory");
    } else {
      asm volatile("s_waitcnt vmcnt(0)" ::: "memory");
    }
    HARD_BARRIER();
  }

  dacc += __shfl_xor(dacc, 16);
  dacc += __shfl_xor(dacc, 32);
  float dv[4];
#pragma unroll
  for (int r = 0; r < 4; ++r) dv[r] = __shfl(dacc, 4 * g + r);

#pragma unroll
  for (int t = 0; t < 4; ++t) {
#pragma unroll
    for (int r = 0; r < 4; ++r) {
      int m = b * 1024 + it0 + 4 * g + r;
      int n = h * 64 + t * 16 + l15;
      AO[(size_t)m * 1024 + n] = f2bf(o[t][r] / dv[r]);
    }
  }
}

// ---------------------------------------------------------------------------
extern "C" void kernel_launch(void* const* d_in, const int* in_sizes, int n_in,
                              void* d_out, int out_size, void* d_ws, size_t ws_size,
                              hipStream_t stream) {
  const float* x  = (const float*)d_in[0];
  const float* WQ = (const float*)d_in[1];
  const float* bQ = (const float*)d_in[2];
  const float* WK = (const float*)d_in[3];
  const float* bK = (const float*)d_in[4];
  const float* WV = (const float*)d_in[5];
  const float* bV = (const float*)d_in[6];
  const float* WO = (const float*)d_in[7];
  const float* bO = (const float*)d_in[8];

  char* base = (char*)d_ws;
  unsigned short* xb  = (unsigned short*)(base);
  unsigned short* WQT = (unsigned short*)(base + (4u  << 20));
  unsigned short* WKT = (unsigned short*)(base + (6u  << 20));
  unsigned short* WVT = (unsigned short*)(base + (8u  << 20));
  unsigned short* WOT = (unsigned short*)(base + (10u << 20));
  unsigned short* Qb  = (unsigned short*)(base + (12u << 20));
  unsigned short* Kb  = (unsigned short*)(base + (16u << 20));
  unsigned short* VTp = (unsigned short*)(base + (20u << 20));
  unsigned short* AOb = (unsigned short*)(base + (24u << 20));
  float* q2  = (float*)(base + (28u << 20));
  float* k2  = (float*)(base + (28u << 20) + (128u << 10));
  float* rnc = (float*)(base + (28u << 20) + (256u << 10));

  prep<<<6144, 256, 0, stream>>>(x, xb, WQ, WK, WV, WO, WQT, WKT, WVT, WOT);

  // fused Q,K,V projections; q2/k2 computed in the Q/K epilogues
  gemm_qkv<<<dim3(16, 16, 3), 256, 0, stream>>>(xb, WQT, WKT, WVT, bQ, bK, bV,
                                                Qb, Kb, VTp, q2, k2, nullptr,
                                                0, 0, 1);

  colsum_mfma<<<dim3(32, 16), 256, 0, stream>>>(Qb, Kb, q2, k2, rnc);
  attn_mfma<<<dim3(32, 16), 256, 0, stream>>>(Qb, Kb, VTp, q2, k2, rnc, AOb);

  gemm_st<<<dim3(32, 16), 256, 0, stream>>>(AOb, WOT, bO, (float*)d_out);
}